// Round 9
// baseline (129.779 us; speedup 1.0000x reference)
//
#include <hip/hip_runtime.h>

// Problem constants
constexpr int NB   = 4;     // batch
constexpr int SEQ  = 2048;  // Q == K
constexpr int CDIM = 128;   // input channels
constexpr int NH   = 8;     // heads
constexpr int HD   = 16;    // head dim

typedef _Float16 h_t;
typedef __attribute__((ext_vector_type(4))) _Float16 h4;
typedef __attribute__((ext_vector_type(8))) _Float16 h8;
typedef __attribute__((ext_vector_type(2))) __fp16   fp2;   // cvt_pkrtz result type
typedef __attribute__((ext_vector_type(4))) float    f4;

// exp(s - 8) == 2^(s*log2e - 8*log2e); log2e is folded into q at projection
// time, so attn computes 2^(S + BIAS) with a single native v_exp_f32.
constexpr float LOG2E = 1.44269504f;
constexpr float BIAS  = -8.0f * LOG2E;   // -11.5415603

// ---------------------------------------------------------------------------
// Kernel 1: QKV projection as f16 MFMA GEMM, weights converted inline.
// q pre-scaled by log2e/sqrt(D) (softmax exp2 + 1/sqrt(D) folded in).
// V is written TRANSPOSED [B,H,D,S] so attn can vector-load V fragments.
// grid (128 row-tiles of 64, 3 mats), 4 waves/block.
// ---------------------------------------------------------------------------
__global__ __launch_bounds__(256)
void proj(const float* __restrict__ qx, const float* __restrict__ kvx,
          const float* __restrict__ wq, const float* __restrict__ wk,
          const float* __restrict__ wv,
          h_t* __restrict__ qh, h_t* __restrict__ kh, h_t* __restrict__ vTh)
{
    const int mat = blockIdx.y;                 // 0=q, 1=k, 2=v
    const int mb  = blockIdx.x * 64;            // row-tile base (8192 rows)
    const int wv_ = threadIdx.x >> 6;           // wave 0..3
    const int ln  = threadIdx.x & 63;
    const int r   = ln & 15, kg = ln >> 4;
    const int row = mb + wv_ * 16 + r;          // A-frag row (m = ln&15)

    const float* x = (mat == 0) ? qx : kvx;
    const float* w = (mat == 0) ? wq : (mat == 1) ? wk : wv;
    h_t*         o = (mat == 0) ? qh : (mat == 1) ? kh : vTh;
    const float xs = (mat == 0) ? 0.25f * LOG2E : 1.0f;

    // A fragments: 4 K-chunks of 32; lane holds k = kg*8 + i (contiguous 8)
    h8 a[4];
    #pragma unroll
    for (int kc = 0; kc < 4; ++kc) {
        const float* xp = x + (size_t)row * CDIM + kc * 32 + kg * 8;
        f4 x0 = *(const f4*)xp;
        f4 x1 = *(const f4*)(xp + 4);
        h8 tf;
        #pragma unroll
        for (int i = 0; i < 4; ++i) {
            tf[i]     = (h_t)(x0[i] * xs);
            tf[4 + i] = (h_t)(x1[i] * xs);
        }
        a[kc] = tf;
    }

    #pragma unroll
    for (int nt = 0; nt < 8; ++nt) {            // out-feature 16-col tiles; h = nt
        f4 acc = {0.f, 0.f, 0.f, 0.f};
        #pragma unroll
        for (int kc = 0; kc < 4; ++kc) {
            const float* wp = w + (size_t)(nt * 16 + r) * CDIM + kc * 32 + kg * 8;
            f4 w0 = *(const f4*)wp;
            f4 w1 = *(const f4*)(wp + 4);
            h8 b;
            #pragma unroll
            for (int i = 0; i < 4; ++i) { b[i] = (h_t)w0[i]; b[4 + i] = (h_t)w1[i]; }
            acc = __builtin_amdgcn_mfma_f32_16x16x32_f16(a[kc], b, acc, 0, 0, 0);
        }
        // D: row(m) = 4*kg+reg, col(n) = r  ->  h = nt, d = r
        #pragma unroll
        for (int reg = 0; reg < 4; ++reg) {
            const int gr = mb + wv_ * 16 + 4 * kg + reg;
            const int b_ = gr >> 11, s = gr & (SEQ - 1);
            if (mat == 2)   // V^T: [B,H,D,S]
                o[(((size_t)b_ * NH + nt) * HD + r) * SEQ + s] = (h_t)acc[reg];
            else            // [B,H,S,D]
                o[(((size_t)b_ * NH + nt) * SEQ + s) * HD + r] = (h_t)acc[reg];
        }
    }
}

// ---------------------------------------------------------------------------
// Kernel 2: MFMA flash attention — NO LDS, NO BARRIERS.
// K/V are tiny per head (64 KB each) and L2-resident; each wave streams its
// fragments straight from global with deep vmcnt pipelining (unroll 4).
// kf: 64 lanes cover 512 contiguous bytes (coalesced dwordx2).
// vf: from V^T, 16 rows x 32 B (L2-served).
// Fixed-shift softmax: S already includes log2e (folded into q); C operand
// carries -8*log2e; one native v_exp_f32 (2^x) per score. P packed with
// cvt_pkrtz. grid (16 q-tiles of 128, 32 bh), 4 waves/block, 32 q rows/wave.
// ---------------------------------------------------------------------------
__global__ __launch_bounds__(256)
void attn(const h_t* __restrict__ qh, const h_t* __restrict__ kh,
          const h_t* __restrict__ vT, float* __restrict__ out)
{
    const int bh  = blockIdx.y;                 // b*8 + h
    const int qt  = blockIdx.x;                 // 16 tiles of 128 q rows
    const int wv_ = threadIdx.x >> 6;
    const int ln  = threadIdx.x & 63;
    const int r   = ln & 15, kg = ln >> 4;

    const size_t hb = (size_t)bh * SEQ * HD;
    const int qb = qt * 128 + wv_ * 32;

    // Q fragments (pre-scaled by log2e/4): B-operand n=q=r, k=d=kg*4+i
    h4 qf0 = *(const h4*)(qh + hb + (size_t)(qb + r)      * HD + kg * 4);
    h4 qf1 = *(const h4*)(qh + hb + (size_t)(qb + 16 + r) * HD + kg * 4);

    // per-lane streaming bases
    const h_t* kp = kh + hb + (size_t)r * HD  + kg * 4;   // +256 halves / chunk
    const h_t* vp = vT + hb + (size_t)r * SEQ + kg * 4;   // +16 halves / chunk

    float l0a = 0.f, l0b = 0.f, l1a = 0.f, l1b = 0.f;
    f4 o0 = {0.f, 0.f, 0.f, 0.f}, o1 = {0.f, 0.f, 0.f, 0.f};
    const f4 cbias = {BIAS, BIAS, BIAS, BIAS};

    #pragma unroll 4
    for (int c = 0; c < SEQ / 16; ++c) {
        // K fragment: A[m=kv=16c+r][k=d=kg*4+i]
        h4 kf = *(const h4*)(kp + c * 16 * HD);
        // V fragment: B[k=kv=16c+4kg+i][n=d=r]
        h4 vf = *(const h4*)(vp + c * 16);

        // S^T chunks (log2-domain, bias pre-folded): D[row=kv=4kg+reg][col=q=r]
        f4 s0 = __builtin_amdgcn_mfma_f32_16x16x16f16(kf, qf0, cbias, 0, 0, 0);
        f4 s1 = __builtin_amdgcn_mfma_f32_16x16x16f16(kf, qf1, cbias, 0, 0, 0);

        const float e00 = __builtin_amdgcn_exp2f(s0[0]);
        const float e01 = __builtin_amdgcn_exp2f(s0[1]);
        const float e02 = __builtin_amdgcn_exp2f(s0[2]);
        const float e03 = __builtin_amdgcn_exp2f(s0[3]);
        const float e10 = __builtin_amdgcn_exp2f(s1[0]);
        const float e11 = __builtin_amdgcn_exp2f(s1[1]);
        const float e12 = __builtin_amdgcn_exp2f(s1[2]);
        const float e13 = __builtin_amdgcn_exp2f(s1[3]);
        l0a += e00 + e01; l0b += e02 + e03;
        l1a += e10 + e11; l1b += e12 + e13;

        union { fp2 c[2]; h4 v; } p0, p1;
        p0.c[0] = __builtin_amdgcn_cvt_pkrtz(e00, e01);
        p0.c[1] = __builtin_amdgcn_cvt_pkrtz(e02, e03);
        p1.c[0] = __builtin_amdgcn_cvt_pkrtz(e10, e11);
        p1.c[1] = __builtin_amdgcn_cvt_pkrtz(e12, e13);

        // P (A-layout in place: m=q=r, k=kv=4kg+reg) . V
        o0 = __builtin_amdgcn_mfma_f32_16x16x16f16(p0.v, vf, o0, 0, 0, 0);
        o1 = __builtin_amdgcn_mfma_f32_16x16x16f16(p1.v, vf, o1, 0, 0, 0);
    }

    // reduce l over the 4 kg partitions (lane (r,kg) holds partial for q-col r)
    float l0 = l0a + l0b, l1 = l1a + l1b;
    l0 += __shfl_xor(l0, 16); l0 += __shfl_xor(l0, 32);
    l1 += __shfl_xor(l1, 16); l1 += __shfl_xor(l1, 32);
    const float i0 = 1.f / l0, i1 = 1.f / l1;

    // epilogue: O row q = 4kg+reg, col d = r ; out [B,Q,H,D] fp32
    const int b_ = bh >> 3, h = bh & 7;
    #pragma unroll
    for (int reg = 0; reg < 4; ++reg) {
        const float v0 = __shfl(i0, 4 * kg + reg);  // lane 4kg+reg has l for that q
        const float v1 = __shfl(i1, 4 * kg + reg);
        const int q0 = qb + 4 * kg + reg;
        const int q1 = q0 + 16;
        out[(((size_t)b_ * SEQ + q0) * NH + h) * HD + r] = o0[reg] * v0;
        out[(((size_t)b_ * SEQ + q1) * NH + h) * HD + r] = o1[reg] * v1;
    }
}

// ---------------------------------------------------------------------------
extern "C" void kernel_launch(void* const* d_in, const int* in_sizes, int n_in,
                              void* d_out, int out_size, void* d_ws, size_t ws_size,
                              hipStream_t stream) {
    const float* qx  = (const float*)d_in[0]; // [B,S,C] f32
    const float* kvx = (const float*)d_in[1]; // [B,S,C] f32
    const float* wq  = (const float*)d_in[2]; // [H*D,C] f32
    const float* wk  = (const float*)d_in[3];
    const float* wv  = (const float*)d_in[4];
    float* out = (float*)d_out;               // [B,Q,H,D] f32

    // workspace layout (f16): q[1M] | k[1M] | vT[1M] = 6 MB
    h_t* qp = (h_t*)d_ws;
    h_t* kp = qp + (size_t)NB * NH * SEQ * HD;
    h_t* vp = kp + (size_t)NB * NH * SEQ * HD;

    proj<<<dim3(128, 3), dim3(256), 0, stream>>>(qx, kvx, wq, wk, wv, qp, kp, vp);
    attn<<<dim3(16, 32), dim3(256), 0, stream>>>(qp, kp, vp, out);
}

// Round 10
// 121.804 us; speedup vs baseline: 1.0655x; 1.0655x over previous
//
#include <hip/hip_runtime.h>

// Problem constants
constexpr int NB   = 4;     // batch
constexpr int SEQ  = 2048;  // Q == K
constexpr int CDIM = 128;   // input channels
constexpr int NH   = 8;     // heads
constexpr int HD   = 16;    // head dim

typedef _Float16 h_t;
typedef __attribute__((ext_vector_type(4))) _Float16 h4;
typedef __attribute__((ext_vector_type(8))) _Float16 h8;
typedef __attribute__((ext_vector_type(2))) __fp16   fp2;   // cvt_pkrtz result type
typedef __attribute__((ext_vector_type(4))) float    f4;

// exp(s - 8) == 2^(s*log2e - 8*log2e); log2e folded into q at projection time,
// so attn computes 2^(S + BIAS) with a single native v_exp_f32 per score.
constexpr float LOG2E = 1.44269504f;
constexpr float BIAS  = -8.0f * LOG2E;   // -11.5415603

// ---------------------------------------------------------------------------
// Kernel 1: QKV projection as f16 MFMA GEMM, weights converted inline.
// q pre-scaled by log2e/sqrt(D). V written TRANSPOSED [B,H,D,S].
// grid (128 row-tiles of 64, 3 mats), 4 waves/block.
// ---------------------------------------------------------------------------
__global__ __launch_bounds__(256)
void proj(const float* __restrict__ qx, const float* __restrict__ kvx,
          const float* __restrict__ wq, const float* __restrict__ wk,
          const float* __restrict__ wv,
          h_t* __restrict__ qh, h_t* __restrict__ kh, h_t* __restrict__ vTh)
{
    const int mat = blockIdx.y;                 // 0=q, 1=k, 2=v
    const int mb  = blockIdx.x * 64;            // row-tile base (8192 rows)
    const int wv_ = threadIdx.x >> 6;           // wave 0..3
    const int ln  = threadIdx.x & 63;
    const int r   = ln & 15, kg = ln >> 4;
    const int row = mb + wv_ * 16 + r;          // A-frag row (m = ln&15)

    const float* x = (mat == 0) ? qx : kvx;
    const float* w = (mat == 0) ? wq : (mat == 1) ? wk : wv;
    h_t*         o = (mat == 0) ? qh : (mat == 1) ? kh : vTh;
    const float xs = (mat == 0) ? 0.25f * LOG2E : 1.0f;

    // A fragments: 4 K-chunks of 32; lane holds k = kg*8 + i (contiguous 8)
    h8 a[4];
    #pragma unroll
    for (int kc = 0; kc < 4; ++kc) {
        const float* xp = x + (size_t)row * CDIM + kc * 32 + kg * 8;
        f4 x0 = *(const f4*)xp;
        f4 x1 = *(const f4*)(xp + 4);
        h8 tf;
        #pragma unroll
        for (int i = 0; i < 4; ++i) {
            tf[i]     = (h_t)(x0[i] * xs);
            tf[4 + i] = (h_t)(x1[i] * xs);
        }
        a[kc] = tf;
    }

    #pragma unroll
    for (int nt = 0; nt < 8; ++nt) {            // out-feature 16-col tiles; h = nt
        f4 acc = {0.f, 0.f, 0.f, 0.f};
        #pragma unroll
        for (int kc = 0; kc < 4; ++kc) {
            const float* wp = w + (size_t)(nt * 16 + r) * CDIM + kc * 32 + kg * 8;
            f4 w0 = *(const f4*)wp;
            f4 w1 = *(const f4*)(wp + 4);
            h8 b;
            #pragma unroll
            for (int i = 0; i < 4; ++i) { b[i] = (h_t)w0[i]; b[4 + i] = (h_t)w1[i]; }
            acc = __builtin_amdgcn_mfma_f32_16x16x32_f16(a[kc], b, acc, 0, 0, 0);
        }
        // D: row(m) = 4*kg+reg, col(n) = r  ->  h = nt, d = r
        #pragma unroll
        for (int reg = 0; reg < 4; ++reg) {
            const int gr = mb + wv_ * 16 + 4 * kg + reg;
            const int b_ = gr >> 11, s = gr & (SEQ - 1);
            if (mat == 2)   // V^T: [B,H,D,S]
                o[(((size_t)b_ * NH + nt) * HD + r) * SEQ + s] = (h_t)acc[reg];
            else            // [B,H,S,D]
                o[(((size_t)b_ * NH + nt) * SEQ + s) * HD + r] = (h_t)acc[reg];
        }
    }
}

// ---------------------------------------------------------------------------
// Kernel 2: MFMA flash attention — no LDS/barriers, MANUAL 2-deep software
// pipeline. Round-9 counters (VGPR=32, all pipes idle) showed the compiler
// issued each chunk's L2 loads serially in front of the dependent
// MFMA->exp->MFMA chain. Here chunks c,c+1 live in registers while loads for
// c+2,c+3 are in flight (~300 issue-cyc lookahead > ~200 cyc L2 latency).
// Tail prefetches overread <=1 KB past K/V — inside the 268 MB workspace.
// grid (16 q-tiles of 128, 32 bh), 4 waves/block, 32 q rows/wave.
// ---------------------------------------------------------------------------
__global__ __launch_bounds__(256)
void attn(const h_t* __restrict__ qh, const h_t* __restrict__ kh,
          const h_t* __restrict__ vT, float* __restrict__ out)
{
    const int bh  = blockIdx.y;                 // b*8 + h
    const int qt  = blockIdx.x;                 // 16 tiles of 128 q rows
    const int wv_ = threadIdx.x >> 6;
    const int ln  = threadIdx.x & 63;
    const int r   = ln & 15, kg = ln >> 4;

    const size_t hb = (size_t)bh * SEQ * HD;
    const int qb = qt * 128 + wv_ * 32;

    // Q fragments (pre-scaled by log2e/4): B-operand n=q=r, k=d=kg*4+i
    h4 qf0 = *(const h4*)(qh + hb + (size_t)(qb + r)      * HD + kg * 4);
    h4 qf1 = *(const h4*)(qh + hb + (size_t)(qb + 16 + r) * HD + kg * 4);

    // per-lane streaming bases
    const h_t* kp = kh + hb + (size_t)r * HD  + kg * 4;   // +256 halves / chunk
    const h_t* vp = vT + hb + (size_t)r * SEQ + kg * 4;   // +16 halves / chunk

    float l0a = 0.f, l0b = 0.f, l1a = 0.f, l1b = 0.f;
    f4 o0 = {0.f, 0.f, 0.f, 0.f}, o1 = {0.f, 0.f, 0.f, 0.f};
    const f4 cbias = {BIAS, BIAS, BIAS, BIAS};

    // pipeline prologue: chunks 0 and 1 in registers
    h4 kfa = *(const h4*)(kp);
    h4 vfa = *(const h4*)(vp);
    h4 kfb = *(const h4*)(kp + 16 * HD);
    h4 vfb = *(const h4*)(vp + 16);

    for (int c = 0; c < SEQ / 16; c += 2) {
        // issue next pair's loads FIRST (in flight during compute below)
        h4 kfn0 = *(const h4*)(kp + (c + 2) * 16 * HD);
        h4 vfn0 = *(const h4*)(vp + (c + 2) * 16);
        h4 kfn1 = *(const h4*)(kp + (c + 3) * 16 * HD);
        h4 vfn1 = *(const h4*)(vp + (c + 3) * 16);

        // ---- chunk c (kfa/vfa) ----
        {
            f4 s0 = __builtin_amdgcn_mfma_f32_16x16x16f16(kfa, qf0, cbias, 0, 0, 0);
            f4 s1 = __builtin_amdgcn_mfma_f32_16x16x16f16(kfa, qf1, cbias, 0, 0, 0);
            const float e00 = __builtin_amdgcn_exp2f(s0[0]);
            const float e01 = __builtin_amdgcn_exp2f(s0[1]);
            const float e02 = __builtin_amdgcn_exp2f(s0[2]);
            const float e03 = __builtin_amdgcn_exp2f(s0[3]);
            const float e10 = __builtin_amdgcn_exp2f(s1[0]);
            const float e11 = __builtin_amdgcn_exp2f(s1[1]);
            const float e12 = __builtin_amdgcn_exp2f(s1[2]);
            const float e13 = __builtin_amdgcn_exp2f(s1[3]);
            l0a += e00 + e01; l0b += e02 + e03;
            l1a += e10 + e11; l1b += e12 + e13;
            union { fp2 cc[2]; h4 v; } p0, p1;
            p0.cc[0] = __builtin_amdgcn_cvt_pkrtz(e00, e01);
            p0.cc[1] = __builtin_amdgcn_cvt_pkrtz(e02, e03);
            p1.cc[0] = __builtin_amdgcn_cvt_pkrtz(e10, e11);
            p1.cc[1] = __builtin_amdgcn_cvt_pkrtz(e12, e13);
            o0 = __builtin_amdgcn_mfma_f32_16x16x16f16(p0.v, vfa, o0, 0, 0, 0);
            o1 = __builtin_amdgcn_mfma_f32_16x16x16f16(p1.v, vfa, o1, 0, 0, 0);
        }
        // ---- chunk c+1 (kfb/vfb) ----
        {
            f4 s0 = __builtin_amdgcn_mfma_f32_16x16x16f16(kfb, qf0, cbias, 0, 0, 0);
            f4 s1 = __builtin_amdgcn_mfma_f32_16x16x16f16(kfb, qf1, cbias, 0, 0, 0);
            const float e00 = __builtin_amdgcn_exp2f(s0[0]);
            const float e01 = __builtin_amdgcn_exp2f(s0[1]);
            const float e02 = __builtin_amdgcn_exp2f(s0[2]);
            const float e03 = __builtin_amdgcn_exp2f(s0[3]);
            const float e10 = __builtin_amdgcn_exp2f(s1[0]);
            const float e11 = __builtin_amdgcn_exp2f(s1[1]);
            const float e12 = __builtin_amdgcn_exp2f(s1[2]);
            const float e13 = __builtin_amdgcn_exp2f(s1[3]);
            l0a += e00 + e01; l0b += e02 + e03;
            l1a += e10 + e11; l1b += e12 + e13;
            union { fp2 cc[2]; h4 v; } p0, p1;
            p0.cc[0] = __builtin_amdgcn_cvt_pkrtz(e00, e01);
            p0.cc[1] = __builtin_amdgcn_cvt_pkrtz(e02, e03);
            p1.cc[0] = __builtin_amdgcn_cvt_pkrtz(e10, e11);
            p1.cc[1] = __builtin_amdgcn_cvt_pkrtz(e12, e13);
            o0 = __builtin_amdgcn_mfma_f32_16x16x16f16(p0.v, vfb, o0, 0, 0, 0);
            o1 = __builtin_amdgcn_mfma_f32_16x16x16f16(p1.v, vfb, o1, 0, 0, 0);
        }

        kfa = kfn0; vfa = vfn0;
        kfb = kfn1; vfb = vfn1;
    }

    // reduce l over the 4 kg partitions (lane (r,kg) holds partial for q-col r)
    float l0 = l0a + l0b, l1 = l1a + l1b;
    l0 += __shfl_xor(l0, 16); l0 += __shfl_xor(l0, 32);
    l1 += __shfl_xor(l1, 16); l1 += __shfl_xor(l1, 32);
    const float i0 = 1.f / l0, i1 = 1.f / l1;

    // epilogue: O row q = 4kg+reg, col d = r ; out [B,Q,H,D] fp32
    const int b_ = bh >> 3, h = bh & 7;
    #pragma unroll
    for (int reg = 0; reg < 4; ++reg) {
        const float v0 = __shfl(i0, 4 * kg + reg);  // lane 4kg+reg has l for that q
        const float v1 = __shfl(i1, 4 * kg + reg);
        const int q0 = qb + 4 * kg + reg;
        const int q1 = q0 + 16;
        out[(((size_t)b_ * SEQ + q0) * NH + h) * HD + r] = o0[reg] * v0;
        out[(((size_t)b_ * SEQ + q1) * NH + h) * HD + r] = o1[reg] * v1;
    }
}

// ---------------------------------------------------------------------------
extern "C" void kernel_launch(void* const* d_in, const int* in_sizes, int n_in,
                              void* d_out, int out_size, void* d_ws, size_t ws_size,
                              hipStream_t stream) {
    const float* qx  = (const float*)d_in[0]; // [B,S,C] f32
    const float* kvx = (const float*)d_in[1]; // [B,S,C] f32
    const float* wq  = (const float*)d_in[2]; // [H*D,C] f32
    const float* wk  = (const float*)d_in[3];
    const float* wv  = (const float*)d_in[4];
    float* out = (float*)d_out;               // [B,Q,H,D] f32

    // workspace layout (f16): q[1M] | k[1M] | vT[1M] = 6 MB
    h_t* qp = (h_t*)d_ws;
    h_t* kp = qp + (size_t)NB * NH * SEQ * HD;
    h_t* vp = kp + (size_t)NB * NH * SEQ * HD;

    proj<<<dim3(128, 3), dim3(256), 0, stream>>>(qx, kvx, wq, wk, wv, qp, kp, vp);
    attn<<<dim3(16, 32), dim3(256), 0, stream>>>(qp, kp, vp, out);
}

// Round 11
// 114.166 us; speedup vs baseline: 1.1368x; 1.0669x over previous
//
#include <hip/hip_runtime.h>

// Problem constants
constexpr int NB   = 4;     // batch
constexpr int SEQ  = 2048;  // Q == K
constexpr int CDIM = 128;   // input channels
constexpr int NH   = 8;     // heads
constexpr int HD   = 16;    // head dim

typedef _Float16 h_t;
typedef __attribute__((ext_vector_type(4))) _Float16 h4;
typedef __attribute__((ext_vector_type(8))) _Float16 h8;
typedef __attribute__((ext_vector_type(2))) __fp16   fp2;   // cvt_pkrtz result type
typedef __attribute__((ext_vector_type(4))) float    f4;

// exp(s - 8) == 2^(s*log2e - 8*log2e); log2e folded into q at projection time,
// so attn computes 2^(S + BIAS) with one native v_exp_f32 per score.
constexpr float LOG2E = 1.44269504f;
constexpr float BIAS  = -8.0f * LOG2E;   // -11.5415603

// ---------------------------------------------------------------------------
// Kernel 1: QKV projection as f16 MFMA GEMM, weights converted inline.
// q pre-scaled by log2e/sqrt(D). K written [B,H,S,D] (already fragment-
// coalesced). V written in MFMA-B-FRAGMENT STREAM order:
//   vF[bh][c][d][j]  (c = kv/16, j = kv%16), 256 halves per chunk
// so attn's vf load is one fully-coalesced 512 B/wave read (round-10 counters
// showed the vT gather = 16 scattered 32-B segments/wave = request-rate wall).
// grid (128 row-tiles of 64, 3 mats), 4 waves/block.
// ---------------------------------------------------------------------------
__global__ __launch_bounds__(256)
void proj(const float* __restrict__ qx, const float* __restrict__ kvx,
          const float* __restrict__ wq, const float* __restrict__ wk,
          const float* __restrict__ wv,
          h_t* __restrict__ qh, h_t* __restrict__ kh, h_t* __restrict__ vF)
{
    const int mat = blockIdx.y;                 // 0=q, 1=k, 2=v
    const int mb  = blockIdx.x * 64;            // row-tile base (8192 rows)
    const int wv_ = threadIdx.x >> 6;           // wave 0..3
    const int ln  = threadIdx.x & 63;
    const int r   = ln & 15, kg = ln >> 4;
    const int row = mb + wv_ * 16 + r;          // A-frag row (m = ln&15)

    const float* x = (mat == 0) ? qx : kvx;
    const float* w = (mat == 0) ? wq : (mat == 1) ? wk : wv;
    h_t*         o = (mat == 0) ? qh : (mat == 1) ? kh : vF;
    const float xs = (mat == 0) ? 0.25f * LOG2E : 1.0f;

    // A fragments: 4 K-chunks of 32; lane holds k = kg*8 + i (contiguous 8)
    h8 a[4];
    #pragma unroll
    for (int kc = 0; kc < 4; ++kc) {
        const float* xp = x + (size_t)row * CDIM + kc * 32 + kg * 8;
        f4 x0 = *(const f4*)xp;
        f4 x1 = *(const f4*)(xp + 4);
        h8 tf;
        #pragma unroll
        for (int i = 0; i < 4; ++i) {
            tf[i]     = (h_t)(x0[i] * xs);
            tf[4 + i] = (h_t)(x1[i] * xs);
        }
        a[kc] = tf;
    }

    #pragma unroll
    for (int nt = 0; nt < 8; ++nt) {            // out-feature 16-col tiles; h = nt
        f4 acc = {0.f, 0.f, 0.f, 0.f};
        #pragma unroll
        for (int kc = 0; kc < 4; ++kc) {
            const float* wp = w + (size_t)(nt * 16 + r) * CDIM + kc * 32 + kg * 8;
            f4 w0 = *(const f4*)wp;
            f4 w1 = *(const f4*)(wp + 4);
            h8 b;
            #pragma unroll
            for (int i = 0; i < 4; ++i) { b[i] = (h_t)w0[i]; b[4 + i] = (h_t)w1[i]; }
            acc = __builtin_amdgcn_mfma_f32_16x16x32_f16(a[kc], b, acc, 0, 0, 0);
        }
        // D: row(m) = 4*kg+reg = seq row, col(n) = r ; head = nt, d = r
        #pragma unroll
        for (int reg = 0; reg < 4; ++reg) {
            const int gr = mb + wv_ * 16 + 4 * kg + reg;
            const int b_ = gr >> 11, s = gr & (SEQ - 1);
            if (mat == 2)   // V fragment stream: [bh][c=s/16][d=r][j=s%16]
                o[(((size_t)b_ * NH + nt) * 128 + (s >> 4)) * 256 + r * 16 + (s & 15)]
                    = (h_t)acc[reg];
            else            // [B,H,S,D]
                o[(((size_t)b_ * NH + nt) * SEQ + s) * HD + r] = (h_t)acc[reg];
        }
    }
}

// ---------------------------------------------------------------------------
// Kernel 2: MFMA flash attention — no LDS, no barriers, both K and V streamed
// as fully-coalesced 512 B/wave fragment reads, 2-deep register pipeline.
// Single Q-fragment per wave (16 q rows) -> grid (32,32) = 1024 blocks =
// 4 blocks/CU = 4 waves/SIMD (round-10's 2/SIMD couldn't hide latency);
// the 4 co-resident blocks share one bh's K/V stream -> L1 reuse.
// Tail prefetch overreads <= 1 KB past each tensor — inside the workspace.
// ---------------------------------------------------------------------------
__global__ __launch_bounds__(256)
void attn(const h_t* __restrict__ qh, const h_t* __restrict__ kh,
          const h_t* __restrict__ vF, float* __restrict__ out)
{
    const int bh  = blockIdx.y;                 // b*8 + h
    const int wv_ = threadIdx.x >> 6;
    const int ln  = threadIdx.x & 63;
    const int r   = ln & 15, kg = ln >> 4;

    const size_t hb = (size_t)bh * SEQ * HD;    // per-head offset (vF same size)
    const int qb = blockIdx.x * 64 + wv_ * 16;

    // Q fragment (pre-scaled by log2e/4): B-operand n=q=r, k=d=kg*4+i
    h4 qf = *(const h4*)(qh + hb + (size_t)(qb + r) * HD + kg * 4);

    // per-lane streaming bases; both advance 256 halves (512 B/wave) per chunk
    const h_t* kp = kh + hb + r * HD + kg * 4;
    const h_t* vp = vF + hb + r * 16 + kg * 4;

    float la = 0.f, lb = 0.f;
    f4 o = {0.f, 0.f, 0.f, 0.f};
    const f4 cbias = {BIAS, BIAS, BIAS, BIAS};

    // pipeline prologue: chunks 0 and 1 in registers
    h4 kfa = *(const h4*)(kp);
    h4 vfa = *(const h4*)(vp);
    h4 kfb = *(const h4*)(kp + 256);
    h4 vfb = *(const h4*)(vp + 256);

    for (int c = 0; c < SEQ / 16; c += 2) {
        // issue next pair's loads FIRST (in flight during compute below)
        h4 kfn0 = *(const h4*)(kp + (c + 2) * 256);
        h4 vfn0 = *(const h4*)(vp + (c + 2) * 256);
        h4 kfn1 = *(const h4*)(kp + (c + 3) * 256);
        h4 vfn1 = *(const h4*)(vp + (c + 3) * 256);

        // ---- chunk c ----
        {
            f4 s = __builtin_amdgcn_mfma_f32_16x16x16f16(kfa, qf, cbias, 0, 0, 0);
            const float e0 = __builtin_amdgcn_exp2f(s[0]);
            const float e1 = __builtin_amdgcn_exp2f(s[1]);
            const float e2 = __builtin_amdgcn_exp2f(s[2]);
            const float e3 = __builtin_amdgcn_exp2f(s[3]);
            la += e0 + e1; lb += e2 + e3;
            union { fp2 cc[2]; h4 v; } p;
            p.cc[0] = __builtin_amdgcn_cvt_pkrtz(e0, e1);
            p.cc[1] = __builtin_amdgcn_cvt_pkrtz(e2, e3);
            o = __builtin_amdgcn_mfma_f32_16x16x16f16(p.v, vfa, o, 0, 0, 0);
        }
        // ---- chunk c+1 ----
        {
            f4 s = __builtin_amdgcn_mfma_f32_16x16x16f16(kfb, qf, cbias, 0, 0, 0);
            const float e0 = __builtin_amdgcn_exp2f(s[0]);
            const float e1 = __builtin_amdgcn_exp2f(s[1]);
            const float e2 = __builtin_amdgcn_exp2f(s[2]);
            const float e3 = __builtin_amdgcn_exp2f(s[3]);
            la += e0 + e1; lb += e2 + e3;
            union { fp2 cc[2]; h4 v; } p;
            p.cc[0] = __builtin_amdgcn_cvt_pkrtz(e0, e1);
            p.cc[1] = __builtin_amdgcn_cvt_pkrtz(e2, e3);
            o = __builtin_amdgcn_mfma_f32_16x16x16f16(p.v, vfb, o, 0, 0, 0);
        }

        kfa = kfn0; vfa = vfn0;
        kfb = kfn1; vfb = vfn1;
    }

    // reduce l over the 4 kg partitions (lane (r,kg) holds partial for q-col r)
    float l = la + lb;
    l += __shfl_xor(l, 16);
    l += __shfl_xor(l, 32);
    const float inv = 1.f / l;

    // epilogue: O row q = 4kg+reg, col d = r ; out [B,Q,H,D] fp32
    const int b_ = bh >> 3, h = bh & 7;
    #pragma unroll
    for (int reg = 0; reg < 4; ++reg) {
        const float iv = __shfl(inv, 4 * kg + reg);  // lane 4kg+reg has l for that q
        const int q = qb + 4 * kg + reg;
        out[(((size_t)b_ * SEQ + q) * NH + h) * HD + r] = o[reg] * iv;
    }
}

// ---------------------------------------------------------------------------
extern "C" void kernel_launch(void* const* d_in, const int* in_sizes, int n_in,
                              void* d_out, int out_size, void* d_ws, size_t ws_size,
                              hipStream_t stream) {
    const float* qx  = (const float*)d_in[0]; // [B,S,C] f32
    const float* kvx = (const float*)d_in[1]; // [B,S,C] f32
    const float* wq  = (const float*)d_in[2]; // [H*D,C] f32
    const float* wk  = (const float*)d_in[3];
    const float* wv  = (const float*)d_in[4];
    float* out = (float*)d_out;               // [B,Q,H,D] f32

    // workspace layout (f16): q[1M] | k[1M] | vF[1M] = 6 MB
    h_t* qp = (h_t*)d_ws;
    h_t* kp = qp + (size_t)NB * NH * SEQ * HD;
    h_t* vp = kp + (size_t)NB * NH * SEQ * HD;

    proj<<<dim3(128, 3), dim3(256), 0, stream>>>(qx, kvx, wq, wk, wv, qp, kp, vp);
    attn<<<dim3(32, 32), dim3(256), 0, stream>>>(qp, kp, vp, out);
}